// Round 9
// baseline (58.866 us; speedup 1.0000x reference)
//
#include <hip/hip_runtime.h>
#include <math.h>

#define B_   32
#define N_   512
#define W_   256
#define BN_  (B_*N_)        // 16384
#define NBLK_A 2048         // kA: 8 rows/block (4 waves x 2 rows)
#define RHOG   2048         // rho partial groups (one per kA BLOCK)

__device__ __forceinline__ float wave_reduce_sum64(float v) {
#pragma unroll
    for (int m = 32; m >= 1; m >>= 1) v += __shfl_xor(v, m);
    return v;
}

// ---------------------------------------------------------------------------
// Kernel Pre: block 0 = normalize se -> en_g (once, float4).
//             block 1 = stage weights to LDS, compute Gamma/gsz/gA.
// ---------------------------------------------------------------------------
__global__ __launch_bounds__(256) void kPre(
    const float* __restrict__ se,
    const float* __restrict__ w2, const float* __restrict__ b2,
    const float* __restrict__ w3, const float* __restrict__ b3,
    const float* __restrict__ w5, const float* __restrict__ b5,
    const float* __restrict__ w7, const float* __restrict__ b7,
    const float* __restrict__ enc_w, const float* __restrict__ enc_b,
    const float* __restrict__ g0w, const float* __restrict__ g0s, const float* __restrict__ g0d,
    const float* __restrict__ g1w, const float* __restrict__ g1s, const float* __restrict__ g1d,
    float* __restrict__ en_g, float* __restrict__ ws_gam,
    float* __restrict__ ws_gsz, float* __restrict__ ws_gA)
{
    const int tid = threadIdx.x;

    if (blockIdx.x == 0) {
        // -------- normalize all 512 rows (2 per thread, vectorized) --------
#pragma unroll
        for (int p = 0; p < 2; ++p) {
            const int rr = tid + p * 256;
            const float4 a = reinterpret_cast<const float4*>(se)[rr * 2];
            const float4 b = reinterpret_cast<const float4*>(se)[rr * 2 + 1];
            const float ss = a.x*a.x + a.y*a.y + a.z*a.z + a.w*a.w
                           + b.x*b.x + b.y*b.y + b.z*b.z + b.w*b.w;
            const float inv = 1.0f / fmaxf(sqrtf(ss), 1e-12f);
            float4 oa = a, ob = b;
            oa.x*=inv; oa.y*=inv; oa.z*=inv; oa.w*=inv;
            ob.x*=inv; ob.y*=inv; ob.z*=inv; ob.w*=inv;
            reinterpret_cast<float4*>(en_g)[rr * 2]     = oa;
            reinterpret_cast<float4*>(en_g)[rr * 2 + 1] = ob;
        }
        return;
    }

    // -------- setup block: stage weights -> LDS, then compute --------
    __shared__ float L[1432];
    // offsets
    const int oW2=0, oW3=32, oW5=80, oW7=160;
    const int oB2=272, oB3=288, oB5=304, oB7=320;
    const int oEW=336, oEB=848, oG0=856, oG1=1112, oAV=1368;
#define CPY(off, src, n) for (int t = tid; t < (n); t += 256) L[(off)+t] = (src)[t];
    CPY(oW2, w2, 32)  CPY(oW3, w3, 48)  CPY(oW5, w5, 80)  CPY(oW7, w7, 112)
    CPY(oB2, b2, 16)  CPY(oB3, b3, 16)  CPY(oB5, b5, 16)  CPY(oB7, b7, 16)
    CPY(oEW, enc_w, 512)  CPY(oEB, enc_b, 8)
    CPY(oG0, g0w, 256)    CPY(oG1, g1w, 256)
    CPY(oAV, g0s, 16) CPY(oAV+16, g0d, 16) CPY(oAV+32, g1s, 16) CPY(oAV+48, g1d, 16)
#undef CPY
    __syncthreads();

    if (tid < 64) {
        // Gamma[zi][t] (t=0..6 <-> S,P1,P2,P3,Q1,Q2,Q3), [zi][7] = beta[zi]
        const int zi = tid & 7, t = tid >> 3;
        float acc = (t == 7) ? L[oEB + zi] : 0.f;
#define GAM_KI(BASE_C, OFFW, OFFB, KK)                                          \
        {                                                                       \
            const int k = KK; const int pl = (k - 1) >> 1;                      \
            _Pragma("unroll")                                                   \
            for (int ch = 0; ch < 16; ++ch) {                                   \
                float a;                                                        \
                if (t == 7) a = L[OFFB + ch];                                   \
                else if (t == 0) {                                              \
                    a = 0.f;                                                    \
                    _Pragma("unroll")                                           \
                    for (int j = 0; j < k; ++j) a += L[OFFW + ch*k + j];        \
                    a *= (1.f/(float)W_);                                       \
                } else if (t <= 3) {                                            \
                    const int j = pl + t;                                       \
                    a = (j < k) ? -L[OFFW + ch*k + j]*(1.f/(float)W_) : 0.f;    \
                } else {                                                        \
                    const int j = pl - (t - 3);                                 \
                    a = (j >= 0) ? -L[OFFW + ch*k + j]*(1.f/(float)W_) : 0.f;   \
                }                                                               \
                acc += a * L[oEW + (BASE_C + ch)*8 + zi];                       \
            }                                                                   \
        }
        GAM_KI(0,  oW2, oB2, 2)
        GAM_KI(16, oW3, oB3, 3)
        GAM_KI(32, oW5, oB5, 5)
        GAM_KI(48, oW7, oB7, 7)
#undef GAM_KI
        ws_gam[zi*8+t] = acc;
    } else if (tid < 96) {
        // gsz[q][f] = (W_q @ a_q)[f] (z rows); q = src0,dst0,src1,dst1
        const int q = (tid-64) >> 3, f = (tid-64) & 7;
        const int gw = (q >> 1) ? oG1 : oG0;
        const int av = oAV + q*16;
        float v = 0.f;
#pragma unroll
        for (int d = 0; d < 16; ++d) v += L[gw + f*16+d] * L[av + d];
        ws_gsz[q*8+f] = v;
    } else if (tid < 128) {
        // gA[q][f] = (W_q @ a_q)[8+f] (se rows)
        const int q = (tid-96) >> 3, f = (tid-96) & 7;
        const int gw = (q >> 1) ? oG1 : oG0;
        const int av = oAV + q*16;
        float v = 0.f;
#pragma unroll
        for (int d = 0; d < 16; ++d) v += L[gw + (8+f)*16+d] * L[av + d];
        ws_gA[q*8+f] = v;
    }
}

// ---------------------------------------------------------------------------
// Kernel Top: one wave per row. sim row in registers (v[8]/lane) from en_g
// (L2-hot), then 20-round butterfly argmax. No LDS, no syncthreads.
// ---------------------------------------------------------------------------
__global__ __launch_bounds__(256) void kTop(const float* __restrict__ en_g,
                                            int* __restrict__ adj)
{
    const int wave = threadIdx.x >> 6;
    const int lane = threadIdx.x & 63;
    const int i = (blockIdx.x << 2) + wave;

    const float4 ei0 = reinterpret_cast<const float4*>(en_g)[i * 2];
    const float4 ei1 = reinterpret_cast<const float4*>(en_g)[i * 2 + 1];

    float v[8];
#pragma unroll
    for (int q = 0; q < 8; ++q) {
        const int j = (q << 6) + lane;
        const float4 a = reinterpret_cast<const float4*>(en_g)[j * 2];
        const float4 b = reinterpret_cast<const float4*>(en_g)[j * 2 + 1];
        const float d = ei0.x*a.x + ei0.y*a.y + ei0.z*a.z + ei0.w*a.w
                      + ei1.x*b.x + ei1.y*b.y + ei1.z*b.z + ei1.w*b.w;
        v[q] = (j == i) ? -3.4e38f : d * 0.35355339059327373f;   // 1/sqrt(8)
    }

    int cnt = 1;
    if (lane == 0) adj[i * 24 + 1] = i;          // self first
    for (int it = 0; it < 20; ++it) {
        float bv = v[0]; int bq = 0;
#pragma unroll
        for (int q = 1; q < 8; ++q) if (v[q] > bv) { bv = v[q]; bq = q; }
        int bj = (bq << 6) + lane;
#pragma unroll
        for (int m = 32; m >= 1; m >>= 1) {
            const float ov = __shfl_xor(bv, m);
            const int   oj = __shfl_xor(bj, m);
            if (ov > bv || (ov == bv && oj < bj)) { bv = ov; bj = oj; }
        }
        if (bv <= 0.f) break;                     // relu masks the rest
        if (lane == 0) adj[i * 24 + 1 + cnt] = bj;
        cnt++;
        const int wq = bj >> 6, wl = bj & 63;
#pragma unroll
        for (int q = 0; q < 8; ++q) if (q == wq && lane == wl) v[q] = -3.4e38f;
    }
    if (lane == 0) adj[i * 24] = cnt;
}

// ---------------------------------------------------------------------------
// Kernel A: 2 rows/wave. z computed affinely (Gamma) by ALL lanes.
// rho partials reduced per BLOCK (LDS + 1 barrier) -> ws_rho[2048][8].
// ---------------------------------------------------------------------------
__global__ __launch_bounds__(256) void kA(
    const float* __restrict__ x,
    const float* __restrict__ dec_w, const float* __restrict__ dec_b,
    const float* __restrict__ g0w, const float* __restrict__ g1w,
    const float* __restrict__ se,
    const float* __restrict__ ws_gam, const float* __restrict__ ws_gsz,
    const float* __restrict__ ws_gA,
    float* __restrict__ out_recon, float* __restrict__ out_sdev,
    float* __restrict__ ws_h, float* __restrict__ ws_e, float* __restrict__ ws_rho)
{
    __shared__ float lds_rho[4][8];
    const int wave = threadIdx.x >> 6;
    const int lane = threadIdx.x & 63;
    const int r0 = (blockIdx.x << 3) + (wave << 1);
    const int n0 = r0 & (N_ - 1), n1 = (r0 + 1) & (N_ - 1);

    // ---- row loads
    const float4 xv0 = reinterpret_cast<const float4*>(x)[(size_t)r0 * 64 + lane];
    const float4 xv1 = reinterpret_cast<const float4*>(x)[(size_t)(r0+1) * 64 + lane];
    const float4 ph0 = reinterpret_cast<const float4*>(x)[(size_t)r0 * 64];
    const float4 pt0 = reinterpret_cast<const float4*>(x)[(size_t)r0 * 64 + 63];
    const float4 ph1 = reinterpret_cast<const float4*>(x)[(size_t)(r0+1) * 64];
    const float4 pt1 = reinterpret_cast<const float4*>(x)[(size_t)(r0+1) * 64 + 63];

    float S0 = xv0.x + xv0.y + xv0.z + xv0.w;
    float S1 = xv1.x + xv1.y + xv1.z + xv1.w;
#pragma unroll
    for (int m = 32; m >= 1; m >>= 1) { S0 += __shfl_xor(S0, m); S1 += __shfl_xor(S1, m); }

    const float P10 = ph0.x, P20 = P10 + ph0.y, P30 = P20 + ph0.z;
    const float Q10 = pt0.w, Q20 = Q10 + pt0.z, Q30 = Q20 + pt0.y;
    const float P11 = ph1.x, P21 = P11 + ph1.y, P31 = P21 + ph1.z;
    const float Q11 = pt1.w, Q21 = Q11 + pt1.z, Q31 = Q21 + pt1.y;

    // ---- z: all lanes, affine in u (Gamma is L1-hot: 64 floats)
    float z0[8], z1[8];
#pragma unroll
    for (int zi = 0; zi < 8; ++zi) {
        const float4 g0 = reinterpret_cast<const float4*>(ws_gam)[zi * 2];
        const float4 g1 = reinterpret_cast<const float4*>(ws_gam)[zi * 2 + 1];
        z0[zi] = g1.w + g0.x*S0 + g0.y*P10 + g0.z*P20 + g0.w*P30
                       + g1.x*Q10 + g1.y*Q20 + g1.z*Q30;
        z1[zi] = g1.w + g0.x*S1 + g0.y*P11 + g0.z*P21 + g0.w*P31
                       + g1.x*Q11 + g1.y*Q21 + g1.z*Q31;
    }

    // ---- recon rows
    {
        const float4 db = reinterpret_cast<const float4*>(dec_b)[lane];
        float4 rec0 = db, rec1 = db;
#pragma unroll
        for (int zi = 0; zi < 8; ++zi) {
            const float4 dw = reinterpret_cast<const float4*>(dec_w)[zi * 64 + lane];
            rec0.x += z0[zi]*dw.x; rec0.y += z0[zi]*dw.y; rec0.z += z0[zi]*dw.z; rec0.w += z0[zi]*dw.w;
            rec1.x += z1[zi]*dw.x; rec1.y += z1[zi]*dw.y; rec1.z += z1[zi]*dw.z; rec1.w += z1[zi]*dw.w;
        }
        reinterpret_cast<float4*>(out_recon)[(size_t)r0 * 64 + lane] = rec0;
        reinterpret_cast<float4*>(out_recon)[(size_t)(r0+1) * 64 + lane] = rec1;
    }

    // ---- act stats: lanes 0-15 (zi=lane&7, rr=lane>>3); static select of z
    if (lane < 16) {
        const int zi = lane & 7;
        const int rr = lane >> 3;
        float zl = 0.f;
#pragma unroll
        for (int p = 0; p < 8; ++p)
            zl = (zi == p) ? (rr ? z1[p] : z0[p]) : zl;
        const float a = 1.0f / (1.0f + __expf(-zl));
        float sd = fabsf(a - 0.05f);
        sd += __shfl_xor(sd, 1); sd += __shfl_xor(sd, 2); sd += __shfl_xor(sd, 4);
        if (zi == 0) out_sdev[r0 + rr] = sd * 0.125f;
        const float rho = a + __shfl_xor(a, 8);     // row0+row1 per zi
        if (lane < 8) lds_rho[wave][lane] = rho;
    }

    // ---- GAT h (lanes 0-31) and e (lanes 32-39): se terms inline
    if (lane < 32) {
        const float* gw = (lane >> 4) ? g1w : g0w;
        const int dd = lane & 15;
        float gwz[16];
#pragma unroll
        for (int f = 0; f < 16; ++f) gwz[f] = gw[f * 16 + dd];
        float h0 = 0.f, h1 = 0.f;
#pragma unroll
        for (int f = 0; f < 8; ++f) { h0 += z0[f] * gwz[f]; h1 += z1[f] * gwz[f]; }
#pragma unroll
        for (int f = 0; f < 8; ++f) {
            h0 += se[n0 * 8 + f] * gwz[8 + f];
            h1 += se[n1 * 8 + f] * gwz[8 + f];
        }
        ws_h[(size_t)r0 * 32 + lane] = h0;
        ws_h[(size_t)(r0+1) * 32 + lane] = h1;
    } else if (lane < 40) {
        const int q = (lane - 32) & 3;          // src0,dst0,src1,dst1
        const int rr = (lane - 32) >> 2;
        const int nn = rr ? n1 : n0;
        float v = 0.f;
#pragma unroll
        for (int f = 0; f < 8; ++f) v += se[nn * 8 + f] * ws_gA[q * 8 + f];
#pragma unroll
        for (int f = 0; f < 8; ++f) v += (rr ? z1[f] : z0[f]) * ws_gsz[q * 8 + f];
        ws_e[(size_t)(r0 + rr) * 4 + q] = v;
    }

    // ---- block-level rho reduction: 4 waves -> 1 group of 8
    __syncthreads();
    if (threadIdx.x < 8) {
        const float t = lds_rho[0][threadIdx.x] + lds_rho[1][threadIdx.x]
                      + lds_rho[2][threadIdx.x] + lds_rho[3][threadIdx.x];
        ws_rho[(size_t)blockIdx.x * 8 + threadIdx.x] = t;
    }
}

// ---------------------------------------------------------------------------
// Kernel D: sparse GAT aggregation (lane-parallel softmax) + proj(ELU) + head
// half-wave (32 lanes) per (b,i) row; 8 rows per 256-thread block.
// Block 0 reduces rho partials -> KL with ALL 256 threads.
// ---------------------------------------------------------------------------
__global__ __launch_bounds__(256) void kD(
    const float* __restrict__ ws_h, const float* __restrict__ ws_e,
    const int* __restrict__ adj,
    const float* __restrict__ proj_w, const float* __restrict__ proj_b,
    const float* __restrict__ head_w, const float* __restrict__ head_b,
    float* __restrict__ out_pred,
    const float* __restrict__ ws_rho, float* __restrict__ out_kl)
{
    __shared__ float red[4][8];
    const int lane = threadIdx.x & 63;
    const int wave = threadIdx.x >> 6;
    const int half = lane >> 5;
    const int t32 = lane & 31;                // phase1: neighbor slot; phase2: channel d
    const int ri = (wave << 1) + half;
    const int r = (blockIdx.x << 3) + ri;     // (b,i) row
    const int b = r >> 9;
    const int i = r & (N_ - 1);
    const int cnt = adj[i * 24];

    // own-row attention terms (esrc_h0, edst_h0, esrc_h1, edst_h1)
    const float4 er = reinterpret_cast<const float4*>(ws_e)[r];

    // ---- phase 1: lane t owns neighbor t (cnt <= 21)
    const int j = (t32 < cnt) ? adj[i * 24 + 1 + t32] : i;
    const int rj = (b << 9) | j;
    const float4 ejv = reinterpret_cast<const float4*>(ws_e)[rj];
    float e0 = er.x + ejv.y;  e0 = (e0 >= 0.f) ? e0 : 0.2f * e0;
    float e1 = er.z + ejv.w;  e1 = (e1 >= 0.f) ? e1 : 0.2f * e1;
    if (t32 >= cnt) { e0 = -3.4e38f; e1 = -3.4e38f; }
    float m0 = e0, m1 = e1;
#pragma unroll
    for (int m = 16; m >= 1; m >>= 1) {
        m0 = fmaxf(m0, __shfl_xor(m0, m));
        m1 = fmaxf(m1, __shfl_xor(m1, m));
    }
    float w0 = (t32 < cnt) ? __expf(e0 - m0) : 0.f;
    float w1 = (t32 < cnt) ? __expf(e1 - m1) : 0.f;
    float s0 = w0, s1 = w1;
#pragma unroll
    for (int m = 16; m >= 1; m >>= 1) {
        s0 += __shfl_xor(s0, m);
        s1 += __shfl_xor(s1, m);
    }

    // ---- phase 2: channel d = t32; gather h with independent (unrolled) loads.
    // Both weight shuffles execute CONVERGENTLY, then per-lane select (head-
    // divergent shuffle is UB: ds_bpermute from exec-masked-off lane).
    const int d = t32;
    const int head = d >> 4;
    const float sinv = 1.0f / (head ? s1 : s0);
    float acc = 0.f;
#pragma unroll
    for (int t = 0; t < 21; ++t) {
        const float wt0 = __shfl(w0, t, 32);
        const float wt1 = __shfl(w1, t, 32);
        const int   jt  = __shfl(j, t, 32);
        const float wt  = head ? wt1 : wt0;
        acc += wt * ws_h[(size_t)((b << 9) | jt) * 32 + d];
    }
    const float hval = acc * sinv;   // fused GAT output channel d of row r

    // ---- proj + ELU + head (all-to-all via shuffles within the 32-half)
    float f = proj_b[d];
#pragma unroll
    for (int dd = 0; dd < 32; ++dd) {
        const float hv = __shfl(hval, dd, 32);
        f += hv * proj_w[dd * 32 + d];
    }
    f = (f > 0.f) ? f : expm1f(f);
    float p = f * head_w[d];
#pragma unroll
    for (int mm = 16; mm >= 1; mm >>= 1) p += __shfl_xor(p, mm);
    if (d == 0) out_pred[r] = p + head_b[0];

    // ---- KL tail: block 0, ALL 256 threads (8 coalesced iterations each)
    if (blockIdx.x == 0) {
        float t8[8] = {0, 0, 0, 0, 0, 0, 0, 0};
        for (int g = (int)threadIdx.x; g < RHOG; g += 256) {
            const float4 a  = reinterpret_cast<const float4*>(ws_rho)[g * 2];
            const float4 bb = reinterpret_cast<const float4*>(ws_rho)[g * 2 + 1];
            t8[0] += a.x;  t8[1] += a.y;  t8[2] += a.z;  t8[3] += a.w;
            t8[4] += bb.x; t8[5] += bb.y; t8[6] += bb.z; t8[7] += bb.w;
        }
#pragma unroll
        for (int m = 32; m >= 1; m >>= 1)
#pragma unroll
            for (int zi = 0; zi < 8; ++zi) t8[zi] += __shfl_xor(t8[zi], m);
        if (lane == 0) {
#pragma unroll
            for (int zi = 0; zi < 8; ++zi) red[wave][zi] = t8[zi];
        }
        __syncthreads();
        if (threadIdx.x == 0) {
            float kl = 0.f;
#pragma unroll
            for (int zi = 0; zi < 8; ++zi) {
                float rh = (red[0][zi] + red[1][zi] + red[2][zi] + red[3][zi])
                           * (1.0f / (float)BN_);
                rh = fminf(fmaxf(rh, 1e-6f), 1.0f - 1e-6f);
                kl += 0.05f * logf(0.05f / rh) + 0.95f * logf(0.95f / (1.0f - rh));
            }
            out_kl[0] = kl;
        }
    }
}

// ---------------------------------------------------------------------------
extern "C" void kernel_launch(void* const* d_in, const int* in_sizes, int n_in,
                              void* d_out, int out_size, void* d_ws, size_t ws_size,
                              hipStream_t stream)
{
    (void)in_sizes; (void)n_in; (void)out_size; (void)ws_size;
    const float* x     = (const float*)d_in[0];
    const float* w2    = (const float*)d_in[1];
    const float* b2    = (const float*)d_in[2];
    const float* w3    = (const float*)d_in[3];
    const float* b3    = (const float*)d_in[4];
    const float* w5    = (const float*)d_in[5];
    const float* b5    = (const float*)d_in[6];
    const float* w7    = (const float*)d_in[7];
    const float* b7    = (const float*)d_in[8];
    const float* enc_w = (const float*)d_in[9];
    const float* enc_b = (const float*)d_in[10];
    const float* dec_w = (const float*)d_in[11];
    const float* dec_b = (const float*)d_in[12];
    const float* se    = (const float*)d_in[13];
    const float* g0w   = (const float*)d_in[14];
    const float* g0s   = (const float*)d_in[15];
    const float* g0d   = (const float*)d_in[16];
    const float* g1w   = (const float*)d_in[17];
    const float* g1s   = (const float*)d_in[18];
    const float* g1d   = (const float*)d_in[19];
    const float* pw    = (const float*)d_in[20];
    const float* pb    = (const float*)d_in[21];
    const float* hw    = (const float*)d_in[22];
    const float* hb    = (const float*)d_in[23];

    float* out       = (float*)d_out;
    float* out_pred  = out;                          // 16384
    float* out_recon = out + 16384;                  // 4194304
    float* out_kl    = out + 16384 + 4194304;        // 1
    float* out_sdev  = out_kl + 1;                   // 16384

    float* ws_h   = (float*)d_ws;                         // BN_*32
    float* ws_e   = ws_h   + (size_t)BN_ * 32;            // BN_*4
    float* ws_rho = ws_e   + (size_t)BN_ * 4;             // RHOG*8
    float* ws_gam = ws_rho + (size_t)RHOG * 8;            // 64
    float* ws_gsz = ws_gam + 64;                          // 32
    float* ws_gA  = ws_gsz + 32;                          // 32
    float* ws_en  = ws_gA  + 32;                          // N_*8
    int*   ws_adj = (int*)(ws_en + (size_t)N_ * 8);       // N_*24 ints

    hipLaunchKernelGGL(kPre, dim3(2), dim3(256), 0, stream,
                       se, w2, b2, w3, b3, w5, b5, w7, b7, enc_w, enc_b,
                       g0w, g0s, g0d, g1w, g1s, g1d,
                       ws_en, ws_gam, ws_gsz, ws_gA);
    hipLaunchKernelGGL(kTop, dim3(N_ / 4), dim3(256), 0, stream, ws_en, ws_adj);
    hipLaunchKernelGGL(kA, dim3(NBLK_A), dim3(256), 0, stream,
                       x, dec_w, dec_b, g0w, g1w, se,
                       ws_gam, ws_gsz, ws_gA,
                       out_recon, out_sdev, ws_h, ws_e, ws_rho);
    hipLaunchKernelGGL(kD, dim3(BN_ / 8), dim3(256), 0, stream,
                       ws_h, ws_e, ws_adj, pw, pb, hw, hb, out_pred,
                       ws_rho, out_kl);
}